// Round 1
// baseline (7166.894 us; speedup 1.0000x reference)
//
#include <hip/hip_runtime.h>

typedef __bf16 bf16x8 __attribute__((ext_vector_type(8)));
typedef float f32x4 __attribute__((ext_vector_type(4)));

#define DIMH 1024
#define SEQL 1024
#define BATCHN 4
#define NROWS (BATCHN*SEQL)   // 4096

// ============================ embedding gather ============================
__global__ __launch_bounds__(256) void embed_kernel(const int* __restrict__ x,
        const float* __restrict__ emb, float* __restrict__ h) {
  int row = blockIdx.x;                       // 0..4095 = b*L + l
  int tok = x[row];
  const f32x4* src = (const f32x4*)(emb + (size_t)tok*DIMH);
  f32x4* dst = (f32x4*)(h + (size_t)row*DIMH);
  dst[threadIdx.x] = src[threadIdx.x];
}

// ============================ layernorm ============================
// one block per row; writes f32 out (if non-null) and bf16 out (if non-null)
__global__ __launch_bounds__(256) void ln_kernel(const float* __restrict__ x,
        const float* __restrict__ w, const float* __restrict__ b,
        float* __restrict__ outf, __bf16* __restrict__ outb) {
  int row = blockIdx.x;
  int tid = threadIdx.x;
  const f32x4* xr = (const f32x4*)(x + (size_t)row*DIMH);
  f32x4 v = xr[tid];
  float s  = v.x+v.y+v.z+v.w;
  float ss = v.x*v.x+v.y*v.y+v.z*v.z+v.w*v.w;
  for (int off=32; off; off>>=1) { s += __shfl_xor(s,off); ss += __shfl_xor(ss,off); }
  __shared__ float sb[8];
  int wave = tid>>6, lane = tid&63;
  if (lane==0){ sb[wave]=s; sb[4+wave]=ss; }
  __syncthreads();
  s  = sb[0]+sb[1]+sb[2]+sb[3];
  ss = sb[4]+sb[5]+sb[6]+sb[7];
  float mean = s*(1.0f/DIMH);
  float var  = ss*(1.0f/DIMH) - mean*mean;
  float rstd = rsqrtf(var + 1e-5f);
  const f32x4* wv = (const f32x4*)w; const f32x4* bv = (const f32x4*)b;
  f32x4 wl = wv[tid], bl = bv[tid];
  f32x4 o;
  o.x = (v.x-mean)*rstd*wl.x + bl.x;
  o.y = (v.y-mean)*rstd*wl.y + bl.y;
  o.z = (v.z-mean)*rstd*wl.z + bl.z;
  o.w = (v.w-mean)*rstd*wl.w + bl.w;
  if (outf) ((f32x4*)(outf + (size_t)row*DIMH))[tid] = o;
  if (outb) {
    __bf16* ob = outb + (size_t)row*DIMH + tid*4;
    ob[0]=(__bf16)o.x; ob[1]=(__bf16)o.y; ob[2]=(__bf16)o.z; ob[3]=(__bf16)o.w;
  }
}

// ============================ S4D diagonal scan ============================
// Equivalent to the reference FFT conv: s[l] = exp(dtA)*s[l-1] + u[l],
// y[l] = 2*Re(sum_n dC_n s_n[l]) + D*u[l], then gelu(tanh approx). Output bf16.
// block = 256 threads = 8 channels x 32 states; grid = B * (H/8) = 512
__global__ __launch_bounds__(256) void s4_scan_kernel(
    const float* __restrict__ u, const float* __restrict__ log_dt,
    const float* __restrict__ A_re, const float* __restrict__ A_im,
    const float* __restrict__ C_re, const float* __restrict__ C_im,
    const float* __restrict__ Dp, __bf16* __restrict__ yout) {
  int b = blockIdx.x >> 7;
  int hblk = blockIdx.x & 127;
  int tid = threadIdx.x;
  int ch = tid >> 5;          // 0..7
  int n  = tid & 31;          // state index
  int h = hblk*8 + ch;
  int hn = h*32 + n;
  float dt  = __expf(log_dt[h]);
  float Are = A_re[hn], Aim = A_im[hn];
  float ar = dt*Are, ai = dt*Aim;
  float er = __expf(ar);
  float sn_, cs_; __sincosf(ai, &sn_, &cs_);
  float lr = er*cs_, li = er*sn_;            // lambda = exp(dtA)
  float wr = lr - 1.0f, wi = li;             // lambda - 1
  float inv = 1.0f/(Are*Are + Aim*Aim);
  float qr = (wr*Are + wi*Aim)*inv;          // (lambda-1)/A
  float qi = (wi*Are - wr*Aim)*inv;
  float Cr = C_re[hn], Ci = C_im[hn];
  float dcr = Cr*qr - Ci*qi;                 // dC = C*(lambda-1)/A
  float dci = Cr*qi + Ci*qr;
  float Dv = Dp[h];
  __shared__ float u_s[64][8];
  __shared__ float y_s[64][8];
  const float* ubase = u + ((size_t)b*SEQL)*DIMH + hblk*8;
  __bf16* ybase = yout + ((size_t)b*SEQL)*DIMH + hblk*8;
  float sr = 0.f, si = 0.f;
  for (int l0=0; l0<SEQL; l0+=64) {
    __syncthreads();
    for (int t=tid; t<512; t+=256) {
      int lt = t>>3, c = t&7;
      u_s[lt][c] = ubase[(size_t)(l0+lt)*DIMH + c];
    }
    __syncthreads();
    for (int lt=0; lt<64; ++lt) {
      float uv = u_s[lt][ch];
      float nsr = fmaf(lr, sr, fmaf(-li, si, uv));
      float nsi = fmaf(lr, si, li*sr);
      sr = nsr; si = nsi;
      float contrib = dcr*sr - dci*si;       // Re(dC * s)
      contrib += __shfl_xor(contrib, 16);
      contrib += __shfl_xor(contrib, 8);
      contrib += __shfl_xor(contrib, 4);
      contrib += __shfl_xor(contrib, 2);
      contrib += __shfl_xor(contrib, 1);
      if (n==0) {
        float yv = 2.0f*contrib + uv*Dv;
        // gelu, tanh approximation (jax.nn.gelu default)
        float t2 = 0.7978845608028654f*(yv + 0.044715f*yv*yv*yv);
        t2 = fminf(t2, 15.0f);               // avoid inf/inf
        float e = __expf(2.0f*t2);
        float th = (e-1.0f)/(e+1.0f);
        y_s[lt][ch] = 0.5f*yv*(1.0f+th);
      }
    }
    __syncthreads();
    for (int t=tid; t<512; t+=256) {
      int lt=t>>3, c=t&7;
      ybase[(size_t)(l0+lt)*DIMH + c] = (__bf16)y_s[lt][c];
    }
  }
}

// ============================ GEMM: C = act(A @ W^T + bias) ============================
// A: bf16 [4096, K]; W: f32 [N_w, K] converted inline; C tile 128x128 per block.
// ACT: 0 = none (+bias, +resid), 1 = GLU sigmoid pair, 2 = GLU silu pair.
// For ACT!=0, W has 2*Nout rows (a rows then g rows), output has Nout cols.
template<int ACT>
__global__ __launch_bounds__(256) void gemm_kernel(
    const __bf16* __restrict__ A, const float* __restrict__ W,
    const float* __restrict__ bias, const float* __restrict__ resid,
    float* __restrict__ outf, __bf16* __restrict__ outb,
    int Nout, int K) {
  int tid = threadIdx.x;
  int wave = tid>>6, lane = tid&63;
  int quad = lane>>4, l16 = lane&15;
  int m0 = blockIdx.y*128 + (wave>>1)*64;
  int n0 = blockIdx.x*128 + (wave&1)*64;
  f32x4 acc[4][4];
  f32x4 accg[4][4];
  f32x4 zero = {0.f,0.f,0.f,0.f};
#pragma unroll
  for (int i=0;i<4;i++)
#pragma unroll
    for (int j=0;j<4;j++){ acc[i][j]=zero; if (ACT) accg[i][j]=zero; }
  const __bf16* aptr[4];
  const float*  wptr[4];
#pragma unroll
  for (int i=0;i<4;i++) aptr[i] = A + (size_t)(m0 + i*16 + l16)*K + quad*8;
#pragma unroll
  for (int j=0;j<4;j++) wptr[j] = W + (size_t)(n0 + j*16 + l16)*K + quad*8;
  size_t goff = (size_t)Nout*K;   // offset to g-half rows of W
  for (int k0=0;k0<K;k0+=32) {
    bf16x8 af[4];
#pragma unroll
    for (int i=0;i<4;i++) af[i] = *(const bf16x8*)(aptr[i] + k0);
    bf16x8 wf[4], wg[4];
#pragma unroll
    for (int j=0;j<4;j++) {
      const f32x4* p = (const f32x4*)(wptr[j] + k0);
      f32x4 lo = p[0], hi = p[1];
      bf16x8 t;
      t[0]=(__bf16)lo.x; t[1]=(__bf16)lo.y; t[2]=(__bf16)lo.z; t[3]=(__bf16)lo.w;
      t[4]=(__bf16)hi.x; t[5]=(__bf16)hi.y; t[6]=(__bf16)hi.z; t[7]=(__bf16)hi.w;
      wf[j]=t;
      if (ACT) {
        const f32x4* pg = (const f32x4*)(wptr[j] + goff + k0);
        f32x4 lo2 = pg[0], hi2 = pg[1];
        bf16x8 t2;
        t2[0]=(__bf16)lo2.x; t2[1]=(__bf16)lo2.y; t2[2]=(__bf16)lo2.z; t2[3]=(__bf16)lo2.w;
        t2[4]=(__bf16)hi2.x; t2[5]=(__bf16)hi2.y; t2[6]=(__bf16)hi2.z; t2[7]=(__bf16)hi2.w;
        wg[j]=t2;
      }
    }
#pragma unroll
    for (int i=0;i<4;i++)
#pragma unroll
      for (int j=0;j<4;j++) {
        acc[i][j] = __builtin_amdgcn_mfma_f32_16x16x32_bf16(af[i], wf[j], acc[i][j], 0,0,0);
        if (ACT)
          accg[i][j] = __builtin_amdgcn_mfma_f32_16x16x32_bf16(af[i], wg[j], accg[i][j], 0,0,0);
      }
  }
  // epilogue — C/D layout: col = lane&15, row = quad*4 + reg  [verified mapping]
#pragma unroll
  for (int i=0;i<4;i++) {
#pragma unroll
    for (int j=0;j<4;j++) {
      int colg = n0 + j*16 + l16;
      float ba = bias[colg];
      float bg = ACT ? bias[Nout + colg] : 0.f;
#pragma unroll
      for (int rr=0;rr<4;rr++) {
        int rowg = m0 + i*16 + quad*4 + rr;
        float v = acc[i][j][rr] + ba;
        if (ACT) {
          float g = accg[i][j][rr] + bg;
          float sg = 1.0f/(1.0f+__expf(-g));
          v = (ACT==1) ? v*sg : v*(g*sg);
        }
        size_t idx = (size_t)rowg*Nout + colg;
        if (resid) v += resid[idx];
        if (outf) outf[idx] = v;
        if (outb) outb[idx] = (__bf16)v;
      }
    }
  }
}

// ============================ host ============================
static void launch_gemm(int act, const __bf16* A, const float* W, const float* bias,
                        const float* resid, float* outf, __bf16* outb,
                        int Nout, int K, hipStream_t s) {
  dim3 g(Nout/128, NROWS/128), b(256);
  if (act==0)      gemm_kernel<0><<<g,b,0,s>>>(A,W,bias,resid,outf,outb,Nout,K);
  else if (act==1) gemm_kernel<1><<<g,b,0,s>>>(A,W,bias,resid,outf,outb,Nout,K);
  else             gemm_kernel<2><<<g,b,0,s>>>(A,W,bias,resid,outf,outb,Nout,K);
}

extern "C" void kernel_launch(void* const* d_in, const int* in_sizes, int n_in,
                              void* d_out, int out_size, void* d_ws, size_t ws_size,
                              hipStream_t stream) {
  (void)in_sizes; (void)n_in; (void)out_size; (void)ws_size;
  const int*   x        = (const int*)d_in[0];
  // d_in[1] = length (unused by reference)
  const float* emb      = (const float*)d_in[2];
  const float* s4_log_dt= (const float*)d_in[3];
  const float* s4_A_re  = (const float*)d_in[4];
  const float* s4_A_im  = (const float*)d_in[5];
  const float* s4_C_re  = (const float*)d_in[6];
  const float* s4_C_im  = (const float*)d_in[7];
  const float* s4_D     = (const float*)d_in[8];
  const float* s4_out_w = (const float*)d_in[9];
  const float* s4_out_b = (const float*)d_in[10];
  const float* norm1_w  = (const float*)d_in[11];
  const float* norm1_b  = (const float*)d_in[12];
  const float* norm2_w  = (const float*)d_in[13];
  const float* norm2_b  = (const float*)d_in[14];
  const float* ff_w1    = (const float*)d_in[15];
  const float* ff_b1    = (const float*)d_in[16];
  const float* ff_w2    = (const float*)d_in[17];
  const float* ff_b2    = (const float*)d_in[18];
  const float* post_w   = (const float*)d_in[19];
  const float* post_b   = (const float*)d_in[20];
  const float* out_w    = (const float*)d_in[21];
  const float* out_b    = (const float*)d_in[22];

  char* ws = (char*)d_ws;
  float*  h    = (float*)(ws + 0);                    // 16 MB  [4096,1024] f32
  float*  r    = (float*)(ws + (16u<<20));            // 16 MB  [4096,1024] f32
  __bf16* yb   = (__bf16*)(ws + (32u<<20));           //  8 MB  [4096,1024] bf16
  __bf16* lnb  = (__bf16*)(ws + (40u<<20));           //  8 MB  [4096,1024] bf16
  __bf16* glub = (__bf16*)(ws + (48u<<20));           // 32 MB  [4096,4096] bf16
  float*  logits = (float*)d_out;                     // [4096,32000] f32

  embed_kernel<<<NROWS,256,0,stream>>>(x, emb, h);

  for (int i=0;i<4;i++) {
    // ---- S4 block: r = LN1(h); r = S4(S4(r)); h = r + h ----
    ln_kernel<<<NROWS,256,0,stream>>>(h, norm1_w+(size_t)i*DIMH, norm1_b+(size_t)i*DIMH, r, lnb);
    for (int j=0;j<2;j++) {
      int k = 2*i+j;
      s4_scan_kernel<<<512,256,0,stream>>>(r, s4_log_dt + (size_t)k*DIMH,
          s4_A_re + (size_t)k*DIMH*32, s4_A_im + (size_t)k*DIMH*32,
          s4_C_re + (size_t)k*DIMH*32, s4_C_im + (size_t)k*DIMH*32,
          s4_D + (size_t)k*DIMH, yb);
      const float* sw    = s4_out_w + (size_t)k*2048*DIMH;
      const float* sbias = s4_out_b + (size_t)k*2048;
      if (j==0)  // r = a*sigmoid(g)
        launch_gemm(1, yb, sw, sbias, nullptr, r, nullptr, DIMH, DIMH, stream);
      else       // h = a*sigmoid(g) + h
        launch_gemm(1, yb, sw, sbias, h, h, nullptr, DIMH, DIMH, stream);
    }
    // ---- FFN block: r = LN2(h); h = (a*silu(g)) @ w2^T + b2 + h ----
    ln_kernel<<<NROWS,256,0,stream>>>(h, norm2_w+(size_t)i*DIMH, norm2_b+(size_t)i*DIMH, r, lnb);
    launch_gemm(2, lnb, ff_w1 + (size_t)i*8192*DIMH, ff_b1 + (size_t)i*8192,
                nullptr, nullptr, glub, 4096, DIMH, stream);
    launch_gemm(0, glub, ff_w2 + (size_t)i*DIMH*4096, ff_b2 + (size_t)i*DIMH,
                h, h, nullptr, DIMH, 4096, stream);
  }

  // ---- post-norm + logits ----
  ln_kernel<<<NROWS,256,0,stream>>>(h, post_w, post_b, r, lnb);
  launch_gemm(0, lnb, out_w, out_b, nullptr, logits, nullptr, 32000, DIMH, stream);
}